// Round 1
// 1082.685 us; speedup vs baseline: 1.7907x; 1.7907x over previous
//
#include <hip/hip_runtime.h>
#include <math.h>

#define HD 128   // hidden dim
#define NG 256   // num graphs
#define NC 10    // classes

// ---------------- CSR build ----------------

__global__ void hist_kernel(const int* __restrict__ dst, int E, int* __restrict__ deg) {
    int e = blockIdx.x * blockDim.x + threadIdx.x;
    if (e < E) atomicAdd(&deg[dst[e]], 1);
}

__global__ void block_sum(const int* __restrict__ deg, int N, int* __restrict__ bsum) {
    __shared__ int sh[256];
    int i = blockIdx.x * 256 + threadIdx.x;
    sh[threadIdx.x] = (i < N) ? deg[i] : 0;
    __syncthreads();
    for (int s = 128; s > 0; s >>= 1) {
        if (threadIdx.x < s) sh[threadIdx.x] += sh[threadIdx.x + s];
        __syncthreads();
    }
    if (threadIdx.x == 0) bsum[blockIdx.x] = sh[0];
}

__global__ void scan_bsum(int* __restrict__ bsum, int nb) {
    if (threadIdx.x == 0 && blockIdx.x == 0) {
        int acc = 0;
        for (int i = 0; i < nb; ++i) { int v = bsum[i]; bsum[i] = acc; acc += v; }
    }
}

__global__ void scan_write(const int* __restrict__ deg, const int* __restrict__ bsum,
                           int N, int E, int* __restrict__ off, int* __restrict__ cursor) {
    __shared__ int sh[256];
    int i = blockIdx.x * 256 + threadIdx.x;
    int v = (i < N) ? deg[i] : 0;
    sh[threadIdx.x] = v;
    __syncthreads();
    for (int s = 1; s < 256; s <<= 1) {
        int t = 0;
        if (threadIdx.x >= s) t = sh[threadIdx.x - s];
        __syncthreads();
        if (threadIdx.x >= s) sh[threadIdx.x] += t;
        __syncthreads();
    }
    if (i < N) {
        int excl = sh[threadIdx.x] - v + bsum[blockIdx.x];
        off[i] = excl;
        cursor[i] = excl;
        if (i == N - 1) off[N] = E;
    }
}

__global__ void fill_csr(const int* __restrict__ src, const int* __restrict__ dst, int E,
                         int* __restrict__ cursor, int* __restrict__ csr_src) {
    int e = blockIdx.x * blockDim.x + threadIdx.x;
    if (e < E) {
        int pos = atomicAdd(&cursor[dst[e]], 1);
        csr_src[pos] = src[e];
    }
}

__global__ void dinv_from_deg(const int* __restrict__ deg, float* __restrict__ dinv, int N) {
    int i = blockIdx.x * blockDim.x + threadIdx.x;
    if (i < N) dinv[i] = rsqrtf((float)deg[i] + 1.0f);
}

// ---------------- conv ----------------

// LDS-tiled fp32 GEMM: out[N,HD] = x[N,F] @ W[F,HD].
// Block tile: BM=64 nodes x 128 cols, K chunked by BK=32.
// Thread micro-tile: 4 nodes x 8 cols (256 threads).
// LDS: xl 64x36 (pad -> 2-way/broadcast reads), wl 32x128. 25.6 KB -> up to 6 blocks/CU.
#define BM 64
#define BK 32

__global__ __launch_bounds__(256) void matmul_tiled(const float* __restrict__ x,
                                                    const float* __restrict__ W,
                                                    float* __restrict__ out, int N, int F) {
    __shared__ float xl[BM][BK + 4];
    __shared__ float wl[BK][HD];
    const int tid = threadIdx.x;
    const int n0 = blockIdx.x * BM;
    const int r4 = (tid >> 4) << 2;    // node offset within tile: 0,4,...,60
    const int c8 = (tid & 15) << 3;    // col offset: 0,8,...,120

    float acc[4][8];
#pragma unroll
    for (int i = 0; i < 4; ++i)
#pragma unroll
        for (int j = 0; j < 8; ++j) acc[i][j] = 0.f;

    for (int k0 = 0; k0 < F; k0 += BK) {
        // stage x chunk: 64 rows x 32 floats = 512 float4 -> 2 per thread
#pragma unroll
        for (int p = 0; p < 2; ++p) {
            int idx = p * 256 + tid;
            int row = idx >> 3;
            int f4 = (idx & 7) << 2;
            int n = n0 + row;
            float4 v = make_float4(0.f, 0.f, 0.f, 0.f);
            if (n < N) v = *(const float4*)(x + (size_t)n * F + k0 + f4);
            *(float4*)&xl[row][f4] = v;
        }
        // stage W chunk: 32 rows x 128 floats = 1024 float4 -> 4 per thread
#pragma unroll
        for (int p = 0; p < 4; ++p) {
            int idx = p * 256 + tid;
            int kk = idx >> 5;
            int j4 = (idx & 31) << 2;
            *(float4*)&wl[kk][j4] = *(const float4*)(W + (size_t)(k0 + kk) * HD + j4);
        }
        __syncthreads();

#pragma unroll 8
        for (int kk = 0; kk < BK; ++kk) {
            float av[4];
            av[0] = xl[r4 + 0][kk];
            av[1] = xl[r4 + 1][kk];
            av[2] = xl[r4 + 2][kk];
            av[3] = xl[r4 + 3][kk];
            float4 w0 = *(const float4*)&wl[kk][c8];
            float4 w1 = *(const float4*)&wl[kk][c8 + 4];
            float wv[8] = {w0.x, w0.y, w0.z, w0.w, w1.x, w1.y, w1.z, w1.w};
#pragma unroll
            for (int i = 0; i < 4; ++i)
#pragma unroll
                for (int j = 0; j < 8; ++j)
                    acc[i][j] += av[i] * wv[j];
        }
        __syncthreads();
    }

#pragma unroll
    for (int i = 0; i < 4; ++i) {
        int n = n0 + r4 + i;
        if (n < N) {
            float4 o0 = make_float4(acc[i][0], acc[i][1], acc[i][2], acc[i][3]);
            float4 o1 = make_float4(acc[i][4], acc[i][5], acc[i][6], acc[i][7]);
            *(float4*)(out + (size_t)n * HD + c8) = o0;
            *(float4*)(out + (size_t)n * HD + c8 + 4) = o1;
        }
    }
}

// gather-aggregate by destination + self-loop + bias + relu, fused.
// 32 lanes per node, float4 per lane over 128 features.
// Edge loop unrolled 4x for memory-level parallelism (independent row loads in flight).
__global__ void gather_kernel(const int* __restrict__ off, const int* __restrict__ csr_src,
                              const float* __restrict__ dinv, const float* __restrict__ xw,
                              const float* __restrict__ b, float* __restrict__ out, int N) {
    int tid = blockIdx.x * blockDim.x + threadIdx.x;
    int n = tid >> 5;
    if (n >= N) return;
    int f4 = (tid & 31) << 2;
    float dn = dinv[n];
    int e0 = off[n], e1 = off[n + 1];
    float ax = 0.f, ay = 0.f, az = 0.f, aw = 0.f;
    int e = e0;
    for (; e + 4 <= e1; e += 4) {
        int s0 = csr_src[e + 0];
        int s1 = csr_src[e + 1];
        int s2 = csr_src[e + 2];
        int s3 = csr_src[e + 3];
        float m0 = dinv[s0] * dn;
        float m1 = dinv[s1] * dn;
        float m2 = dinv[s2] * dn;
        float m3 = dinv[s3] * dn;
        const float4 v0 = *(const float4*)(xw + (size_t)s0 * HD + f4);
        const float4 v1 = *(const float4*)(xw + (size_t)s1 * HD + f4);
        const float4 v2 = *(const float4*)(xw + (size_t)s2 * HD + f4);
        const float4 v3 = *(const float4*)(xw + (size_t)s3 * HD + f4);
        ax += v0.x * m0; ay += v0.y * m0; az += v0.z * m0; aw += v0.w * m0;
        ax += v1.x * m1; ay += v1.y * m1; az += v1.z * m1; aw += v1.w * m1;
        ax += v2.x * m2; ay += v2.y * m2; az += v2.z * m2; aw += v2.w * m2;
        ax += v3.x * m3; ay += v3.y * m3; az += v3.z * m3; aw += v3.w * m3;
    }
    for (; e < e1; ++e) {
        int s = csr_src[e];
        float nrm = dinv[s] * dn;
        const float4 v = *(const float4*)(xw + (size_t)s * HD + f4);
        ax += v.x * nrm; ay += v.y * nrm; az += v.z * nrm; aw += v.w * nrm;
    }
    const float4 xv = *(const float4*)(xw + (size_t)n * HD + f4);
    const float4 bb = *(const float4*)(b + f4);
    float d2 = dn * dn;
    float4 o;
    o.x = ax + xv.x * d2 + bb.x;
    o.y = ay + xv.y * d2 + bb.y;
    o.z = az + xv.z * d2 + bb.z;
    o.w = aw + xv.w * d2 + bb.w;
    o.x = o.x > 0.f ? o.x : 0.f;
    o.y = o.y > 0.f ? o.y : 0.f;
    o.z = o.z > 0.f ? o.z : 0.f;
    o.w = o.w > 0.f ? o.w : 0.f;
    *(float4*)(out + (size_t)n * HD + f4) = o;
}

// ---------------- pooling + head ----------------

__global__ void pool_kernel(const float* __restrict__ h, const int* __restrict__ batch,
                            float* __restrict__ gsum, int N) {
    const int NPB = 256;
    int start = blockIdx.x * NPB;
    int end = min(N, start + NPB);
    int j = threadIdx.x;
    float acc = 0.f;
    int cur = batch[start];
    for (int n = start; n < end; ++n) {
        int g = batch[n];
        if (g != cur) {
            atomicAdd(&gsum[cur * HD + j], acc);
            acc = 0.f;
            cur = g;
        }
        acc += h[(size_t)n * HD + j];
    }
    atomicAdd(&gsum[cur * HD + j], acc);
}

__global__ void count_kernel(const int* __restrict__ batch, float* __restrict__ cnt, int N) {
    int i = blockIdx.x * blockDim.x + threadIdx.x;
    if (i < N) atomicAdd(&cnt[batch[i]], 1.0f);
}

__global__ void lin_kernel(const float* __restrict__ gsum, const float* __restrict__ cnt,
                           const float* __restrict__ W, const float* __restrict__ b,
                           float* __restrict__ out) {
    __shared__ float row[HD];
    int g = blockIdx.x, j = threadIdx.x;
    float c = cnt[g];
    c = c > 1.f ? c : 1.f;
    row[j] = gsum[g * HD + j] / c;
    __syncthreads();
    float s = b[j];
#pragma unroll 8
    for (int k = 0; k < HD; ++k) s += row[k] * W[k * HD + j];
    out[g * HD + j] = s > 0.f ? s : 0.f;
}

__global__ void final_kernel(const float* __restrict__ outg,
                             const float* __restrict__ W3, const float* __restrict__ b3,
                             float* __restrict__ out) {
    __shared__ float c[2 * HD];
    __shared__ float logit[NC];
    __shared__ float lse;
    int g = blockIdx.x, t = threadIdx.x;   // 256 threads
    c[t] = (t < HD) ? outg[g * HD + t] : outg[NG * HD + g * HD + (t - HD)];
    __syncthreads();
    if (t < NC) {
        float s = b3[t];
#pragma unroll 8
        for (int k = 0; k < 2 * HD; ++k) s += c[k] * W3[k * NC + t];
        logit[t] = s;
    }
    __syncthreads();
    if (t == 0) {
        float m = logit[0];
        for (int i = 1; i < NC; ++i) m = fmaxf(m, logit[i]);
        float s = 0.f;
        for (int i = 0; i < NC; ++i) s += expf(logit[i] - m);
        lse = m + logf(s);
    }
    __syncthreads();
    if (t < NC) out[2 * NG * HD + g * NC + t] = logit[t] - lse;
}

// ---------------- host side ----------------

static void run_side(const float* x, int F, const int* ei, int E, const int* batch, int N,
                     const float* w1, const float* b1,
                     const float* ws_w, const float* ws_b,
                     const float* lin_w, const float* lin_b,
                     float* B0, float* B1, float* dinv, float* gsum, float* cnt,
                     int* deg, int* off, int* cursor, int* csr_src, int* bsum,
                     float* out_sec, hipStream_t stream) {
    const int* src = ei;
    const int* dst = ei + E;
    const int nb = (N + 255) / 256;

    // CSR build (once per side, reused for 3 layers)
    hipMemsetAsync(deg, 0, (size_t)N * sizeof(int), stream);
    hist_kernel<<<(E + 255) / 256, 256, 0, stream>>>(dst, E, deg);
    block_sum<<<nb, 256, 0, stream>>>(deg, N, bsum);
    scan_bsum<<<1, 64, 0, stream>>>(bsum, nb);
    scan_write<<<nb, 256, 0, stream>>>(deg, bsum, N, E, off, cursor);
    fill_csr<<<(E + 255) / 256, 256, 0, stream>>>(src, dst, E, cursor, csr_src);
    dinv_from_deg<<<nb, 256, 0, stream>>>(deg, dinv, N);

    const int mm_blocks = (N + BM - 1) / BM;
    const int ga_blocks = (N * 32 + 255) / 256;

    const float* hin = x;
    int Fin = F;
    for (int l = 0; l < 3; ++l) {
        const float* W = (l == 0) ? w1 : ws_w + (size_t)(l - 1) * HD * HD;
        const float* b = (l == 0) ? b1 : ws_b + (size_t)(l - 1) * HD;
        matmul_tiled<<<mm_blocks, 256, 0, stream>>>(hin, W, B0, N, Fin);
        gather_kernel<<<ga_blocks, 256, 0, stream>>>(off, csr_src, dinv, B0, b, B1, N);
        hin = B1;
        Fin = HD;
    }

    hipMemsetAsync(gsum, 0, (size_t)NG * HD * sizeof(float), stream);
    hipMemsetAsync(cnt, 0, (size_t)NG * sizeof(float), stream);
    pool_kernel<<<(N + 255) / 256, 128, 0, stream>>>(B1, batch, gsum, N);
    count_kernel<<<(N + 255) / 256, 256, 0, stream>>>(batch, cnt, N);
    lin_kernel<<<NG, HD, 0, stream>>>(gsum, cnt, lin_w, lin_b, out_sec);
}

extern "C" void kernel_launch(void* const* d_in, const int* in_sizes, int n_in,
                              void* d_out, int out_size, void* d_ws, size_t ws_size,
                              hipStream_t stream) {
    const float* x1  = (const float*)d_in[0];
    const int*   ei1 = (const int*)d_in[1];
    const int*   b1a = (const int*)d_in[2];
    const float* x2  = (const float*)d_in[3];
    const int*   ei2 = (const int*)d_in[4];
    const int*   b2a = (const int*)d_in[5];
    const float* conv1_w = (const float*)d_in[6];
    const float* conv1_b = (const float*)d_in[7];
    const float* convs1_w = (const float*)d_in[8];
    const float* convs1_b = (const float*)d_in[9];
    const float* conv2_w = (const float*)d_in[10];
    const float* conv2_b = (const float*)d_in[11];
    const float* convs2_w = (const float*)d_in[12];
    const float* convs2_b = (const float*)d_in[13];
    const float* lin1_w = (const float*)d_in[14];
    const float* lin1_b = (const float*)d_in[15];
    const float* lin2_w = (const float*)d_in[16];
    const float* lin2_b = (const float*)d_in[17];
    const float* lin3_w = (const float*)d_in[18];
    const float* lin3_b = (const float*)d_in[19];

    const int F1 = 128, F2 = 64;
    const int N1 = in_sizes[2];
    const int N2 = in_sizes[5];
    const int E1 = in_sizes[1] / 2;
    const int E2 = in_sizes[4] / 2;
    const int Emax = E1 > E2 ? E1 : E2;
    const int Nmax = N1 > N2 ? N1 : N2;

    char* ws = (char*)d_ws;
    size_t p = 0;
    auto alloc = [&](size_t bytes) { void* r = ws + p; p = (p + bytes + 255) & ~(size_t)255; return r; };
    float* B0   = (float*)alloc((size_t)Nmax * HD * sizeof(float));
    float* B1   = (float*)alloc((size_t)Nmax * HD * sizeof(float));
    float* dinv = (float*)alloc((size_t)Nmax * sizeof(float));
    float* gsum = (float*)alloc((size_t)NG * HD * sizeof(float));
    float* cnt  = (float*)alloc((size_t)NG * sizeof(float));
    int* deg    = (int*)alloc((size_t)Nmax * sizeof(int));
    int* off    = (int*)alloc((size_t)(Nmax + 1) * sizeof(int));
    int* cursor = (int*)alloc((size_t)Nmax * sizeof(int));
    int* csr_src= (int*)alloc((size_t)Emax * sizeof(int));
    int* bsum   = (int*)alloc(1024 * sizeof(int));

    float* out = (float*)d_out;

    run_side(x1, F1, ei1, E1, b1a, N1, conv1_w, conv1_b, convs1_w, convs1_b,
             lin1_w, lin1_b, B0, B1, dinv, gsum, cnt, deg, off, cursor, csr_src, bsum,
             out, stream);
    run_side(x2, F2, ei2, E2, b2a, N2, conv2_w, conv2_b, convs2_w, convs2_b,
             lin2_w, lin2_b, B0, B1, dinv, gsum, cnt, deg, off, cursor, csr_src, bsum,
             out + NG * HD, stream);

    final_kernel<<<NG, 2 * HD, 0, stream>>>(out, lin3_w, lin3_b, out);
}

// Round 2
// 771.065 us; speedup vs baseline: 2.5143x; 1.4041x over previous
//
#include <hip/hip_runtime.h>
#include <math.h>

#define HD 128   // hidden dim
#define NG 256   // num graphs
#define NC 10    // classes
#define PCH 8    // pool chunks per graph

// ---------------- CSR build ----------------

__global__ void hist_kernel(const int* __restrict__ dst, int E, int* __restrict__ deg) {
    int e = blockIdx.x * blockDim.x + threadIdx.x;
    if (e < E) atomicAdd(&deg[dst[e]], 1);
}

__global__ void block_sum(const int* __restrict__ deg, int N, int* __restrict__ bsum) {
    __shared__ int sh[256];
    int i = blockIdx.x * 256 + threadIdx.x;
    sh[threadIdx.x] = (i < N) ? deg[i] : 0;
    __syncthreads();
    for (int s = 128; s > 0; s >>= 1) {
        if (threadIdx.x < s) sh[threadIdx.x] += sh[threadIdx.x + s];
        __syncthreads();
    }
    if (threadIdx.x == 0) bsum[blockIdx.x] = sh[0];
}

// parallel exclusive scan of block sums (nb <= 256)
__global__ void scan_bsum(int* __restrict__ bsum, int nb) {
    __shared__ int sh[256];
    int t = threadIdx.x;
    int v = (t < nb) ? bsum[t] : 0;
    sh[t] = v;
    __syncthreads();
    for (int s = 1; s < 256; s <<= 1) {
        int tv = 0;
        if (t >= s) tv = sh[t - s];
        __syncthreads();
        sh[t] += tv;
        __syncthreads();
    }
    if (t < nb) bsum[t] = sh[t] - v;   // exclusive
}

__global__ void scan_write(const int* __restrict__ deg, const int* __restrict__ bsum,
                           int N, int E, int* __restrict__ off, int* __restrict__ cursor,
                           float* __restrict__ dinv) {
    __shared__ int sh[256];
    int i = blockIdx.x * 256 + threadIdx.x;
    int v = (i < N) ? deg[i] : 0;
    sh[threadIdx.x] = v;
    __syncthreads();
    for (int s = 1; s < 256; s <<= 1) {
        int t = 0;
        if (threadIdx.x >= s) t = sh[threadIdx.x - s];
        __syncthreads();
        if (threadIdx.x >= s) sh[threadIdx.x] += t;
        __syncthreads();
    }
    if (i < N) {
        int excl = sh[threadIdx.x] - v + bsum[blockIdx.x];
        off[i] = excl;
        cursor[i] = excl;
        dinv[i] = rsqrtf((float)v + 1.0f);
        if (i == N - 1) off[N] = E;
    }
}

__global__ void fill_csr(const int* __restrict__ src, const int* __restrict__ dst, int E,
                         const float* __restrict__ dinv,
                         int* __restrict__ cursor, int* __restrict__ csr_src,
                         float* __restrict__ csr_dinv) {
    int e = blockIdx.x * blockDim.x + threadIdx.x;
    if (e < E) {
        int pos = atomicAdd(&cursor[dst[e]], 1);
        int s = src[e];
        csr_src[pos] = s;
        csr_dinv[pos] = dinv[s];
    }
}

// batch is sorted: graph g spans rows [lb(g), lb(g+1)). One block of NG threads.
__global__ void bounds_kernel(const int* __restrict__ batch, int N,
                              int* __restrict__ bnd, float* __restrict__ cnt) {
    int g = threadIdx.x;   // 0..NG-1
    int lo = 0, hi = N;
    while (lo < hi) { int mid = (lo + hi) >> 1; if (batch[mid] < g) lo = mid + 1; else hi = mid; }
    bnd[g] = lo;
    if (g == 0) bnd[NG] = N;
    int lo2 = lo, hi2 = N, v = g + 1;
    while (lo2 < hi2) { int mid = (lo2 + hi2) >> 1; if (batch[mid] < v) lo2 = mid + 1; else hi2 = mid; }
    cnt[g] = (float)(lo2 - lo);
}

// ---------------- conv ----------------

// LDS-tiled fp32 GEMM: out[N,HD] = x[N,F] @ W[F,HD].
#define BM 64
#define BK 32

__global__ __launch_bounds__(256) void matmul_tiled(const float* __restrict__ x,
                                                    const float* __restrict__ W,
                                                    float* __restrict__ out, int N, int F) {
    __shared__ float xl[BM][BK + 4];
    __shared__ float wl[BK][HD];
    const int tid = threadIdx.x;
    const int n0 = blockIdx.x * BM;
    const int r4 = (tid >> 4) << 2;
    const int c8 = (tid & 15) << 3;

    float acc[4][8];
#pragma unroll
    for (int i = 0; i < 4; ++i)
#pragma unroll
        for (int j = 0; j < 8; ++j) acc[i][j] = 0.f;

    for (int k0 = 0; k0 < F; k0 += BK) {
#pragma unroll
        for (int p = 0; p < 2; ++p) {
            int idx = p * 256 + tid;
            int row = idx >> 3;
            int f4 = (idx & 7) << 2;
            int n = n0 + row;
            float4 v = make_float4(0.f, 0.f, 0.f, 0.f);
            if (n < N) v = *(const float4*)(x + (size_t)n * F + k0 + f4);
            *(float4*)&xl[row][f4] = v;
        }
#pragma unroll
        for (int p = 0; p < 4; ++p) {
            int idx = p * 256 + tid;
            int kk = idx >> 5;
            int j4 = (idx & 31) << 2;
            *(float4*)&wl[kk][j4] = *(const float4*)(W + (size_t)(k0 + kk) * HD + j4);
        }
        __syncthreads();

#pragma unroll 8
        for (int kk = 0; kk < BK; ++kk) {
            float av[4];
            av[0] = xl[r4 + 0][kk];
            av[1] = xl[r4 + 1][kk];
            av[2] = xl[r4 + 2][kk];
            av[3] = xl[r4 + 3][kk];
            float4 w0 = *(const float4*)&wl[kk][c8];
            float4 w1 = *(const float4*)&wl[kk][c8 + 4];
            float wv[8] = {w0.x, w0.y, w0.z, w0.w, w1.x, w1.y, w1.z, w1.w};
#pragma unroll
            for (int i = 0; i < 4; ++i)
#pragma unroll
                for (int j = 0; j < 8; ++j)
                    acc[i][j] += av[i] * wv[j];
        }
        __syncthreads();
    }

#pragma unroll
    for (int i = 0; i < 4; ++i) {
        int n = n0 + r4 + i;
        if (n < N) {
            float4 o0 = make_float4(acc[i][0], acc[i][1], acc[i][2], acc[i][3]);
            float4 o1 = make_float4(acc[i][4], acc[i][5], acc[i][6], acc[i][7]);
            *(float4*)(out + (size_t)n * HD + c8) = o0;
            *(float4*)(out + (size_t)n * HD + c8 + 4) = o1;
        }
    }
}

// gather-aggregate by destination + self-loop + bias + relu, fused.
// 32 lanes per node, float4 per lane over 128 features; csr_dinv streamed (precomputed).
__global__ void gather_kernel(const int* __restrict__ off, const int* __restrict__ csr_src,
                              const float* __restrict__ csr_dinv,
                              const float* __restrict__ dinv, const float* __restrict__ xw,
                              const float* __restrict__ b, float* __restrict__ out, int N) {
    int tid = blockIdx.x * blockDim.x + threadIdx.x;
    int n = tid >> 5;
    if (n >= N) return;
    int f4 = (tid & 31) << 2;
    float dn = dinv[n];
    int e0 = off[n], e1 = off[n + 1];
    float ax = 0.f, ay = 0.f, az = 0.f, aw = 0.f;
    int e = e0;
    for (; e + 4 <= e1; e += 4) {
        int s0 = csr_src[e + 0];
        int s1 = csr_src[e + 1];
        int s2 = csr_src[e + 2];
        int s3 = csr_src[e + 3];
        float m0 = csr_dinv[e + 0] * dn;
        float m1 = csr_dinv[e + 1] * dn;
        float m2 = csr_dinv[e + 2] * dn;
        float m3 = csr_dinv[e + 3] * dn;
        const float4 v0 = *(const float4*)(xw + (size_t)s0 * HD + f4);
        const float4 v1 = *(const float4*)(xw + (size_t)s1 * HD + f4);
        const float4 v2 = *(const float4*)(xw + (size_t)s2 * HD + f4);
        const float4 v3 = *(const float4*)(xw + (size_t)s3 * HD + f4);
        ax += v0.x * m0; ay += v0.y * m0; az += v0.z * m0; aw += v0.w * m0;
        ax += v1.x * m1; ay += v1.y * m1; az += v1.z * m1; aw += v1.w * m1;
        ax += v2.x * m2; ay += v2.y * m2; az += v2.z * m2; aw += v2.w * m2;
        ax += v3.x * m3; ay += v3.y * m3; az += v3.z * m3; aw += v3.w * m3;
    }
    for (; e < e1; ++e) {
        int s = csr_src[e];
        float nrm = csr_dinv[e] * dn;
        const float4 v = *(const float4*)(xw + (size_t)s * HD + f4);
        ax += v.x * nrm; ay += v.y * nrm; az += v.z * nrm; aw += v.w * nrm;
    }
    const float4 xv = *(const float4*)(xw + (size_t)n * HD + f4);
    const float4 bb = *(const float4*)(b + f4);
    float d2 = dn * dn;
    float4 o;
    o.x = ax + xv.x * d2 + bb.x;
    o.y = ay + xv.y * d2 + bb.y;
    o.z = az + xv.z * d2 + bb.z;
    o.w = aw + xv.w * d2 + bb.w;
    o.x = o.x > 0.f ? o.x : 0.f;
    o.y = o.y > 0.f ? o.y : 0.f;
    o.z = o.z > 0.f ? o.z : 0.f;
    o.w = o.w > 0.f ? o.w : 0.f;
    *(float4*)(out + (size_t)n * HD + f4) = o;
}

// ---------------- pooling + head ----------------

// per-graph chunked pool: block (g, c) sums rows [bnd[g]+c :: PCH : bnd[g+1]) into partials.
__global__ void pool_kernel(const float* __restrict__ h, const int* __restrict__ bnd,
                            float* __restrict__ part) {
    int g = blockIdx.x;
    int c = blockIdx.y;
    int j = threadIdx.x;   // HD threads
    int s = bnd[g], e = bnd[g + 1];
    float acc = 0.f;
    for (int n = s + c; n < e; n += PCH) acc += h[(size_t)n * HD + j];
    part[((size_t)c * NG + g) * HD + j] = acc;
}

__global__ void lin_kernel(const float* __restrict__ part, const float* __restrict__ cnt,
                           const float* __restrict__ W, const float* __restrict__ b,
                           float* __restrict__ out) {
    __shared__ float row[HD];
    int g = blockIdx.x, j = threadIdx.x;
    float s0 = 0.f;
#pragma unroll
    for (int c = 0; c < PCH; ++c) s0 += part[((size_t)c * NG + g) * HD + j];
    float c = cnt[g];
    c = c > 1.f ? c : 1.f;
    row[j] = s0 / c;
    __syncthreads();
    float s = b[j];
#pragma unroll 8
    for (int k = 0; k < HD; ++k) s += row[k] * W[k * HD + j];
    out[g * HD + j] = s > 0.f ? s : 0.f;
}

__global__ void final_kernel(const float* __restrict__ outg,
                             const float* __restrict__ W3, const float* __restrict__ b3,
                             float* __restrict__ out) {
    __shared__ float c[2 * HD];
    __shared__ float logit[NC];
    __shared__ float lse;
    int g = blockIdx.x, t = threadIdx.x;   // 256 threads
    c[t] = (t < HD) ? outg[g * HD + t] : outg[NG * HD + g * HD + (t - HD)];
    __syncthreads();
    if (t < NC) {
        float s = b3[t];
#pragma unroll 8
        for (int k = 0; k < 2 * HD; ++k) s += c[k] * W3[k * NC + t];
        logit[t] = s;
    }
    __syncthreads();
    if (t == 0) {
        float m = logit[0];
        for (int i = 1; i < NC; ++i) m = fmaxf(m, logit[i]);
        float s = 0.f;
        for (int i = 0; i < NC; ++i) s += expf(logit[i] - m);
        lse = m + logf(s);
    }
    __syncthreads();
    if (t < NC) out[2 * NG * HD + g * NC + t] = logit[t] - lse;
}

// ---------------- host side ----------------

static void run_side(const float* x, int F, const int* ei, int E, const int* batch, int N,
                     const float* w1, const float* b1,
                     const float* ws_w, const float* ws_b,
                     const float* lin_w, const float* lin_b,
                     float* B0, float* B1, float* dinv, float* part, float* cnt,
                     int* deg, int* off, int* cursor, int* csr_src, float* csr_dinv,
                     int* bsum, int* bnd,
                     float* out_sec, hipStream_t stream) {
    const int* src = ei;
    const int* dst = ei + E;
    const int nb = (N + 255) / 256;

    // CSR build (once per side, reused for 3 layers)
    hipMemsetAsync(deg, 0, (size_t)N * sizeof(int), stream);
    hist_kernel<<<(E + 255) / 256, 256, 0, stream>>>(dst, E, deg);
    block_sum<<<nb, 256, 0, stream>>>(deg, N, bsum);
    scan_bsum<<<1, 256, 0, stream>>>(bsum, nb);
    scan_write<<<nb, 256, 0, stream>>>(deg, bsum, N, E, off, cursor, dinv);
    fill_csr<<<(E + 255) / 256, 256, 0, stream>>>(src, dst, E, dinv, cursor, csr_src, csr_dinv);
    bounds_kernel<<<1, NG, 0, stream>>>(batch, N, bnd, cnt);

    const int mm_blocks = (N + BM - 1) / BM;
    const int ga_blocks = (N * 32 + 255) / 256;

    const float* hin = x;
    int Fin = F;
    for (int l = 0; l < 3; ++l) {
        const float* W = (l == 0) ? w1 : ws_w + (size_t)(l - 1) * HD * HD;
        const float* b = (l == 0) ? b1 : ws_b + (size_t)(l - 1) * HD;
        matmul_tiled<<<mm_blocks, 256, 0, stream>>>(hin, W, B0, N, Fin);
        gather_kernel<<<ga_blocks, 256, 0, stream>>>(off, csr_src, csr_dinv, dinv, B0, b, B1, N);
        hin = B1;
        Fin = HD;
    }

    pool_kernel<<<dim3(NG, PCH), HD, 0, stream>>>(B1, bnd, part);
    lin_kernel<<<NG, HD, 0, stream>>>(part, cnt, lin_w, lin_b, out_sec);
}

extern "C" void kernel_launch(void* const* d_in, const int* in_sizes, int n_in,
                              void* d_out, int out_size, void* d_ws, size_t ws_size,
                              hipStream_t stream) {
    const float* x1  = (const float*)d_in[0];
    const int*   ei1 = (const int*)d_in[1];
    const int*   b1a = (const int*)d_in[2];
    const float* x2  = (const float*)d_in[3];
    const int*   ei2 = (const int*)d_in[4];
    const int*   b2a = (const int*)d_in[5];
    const float* conv1_w = (const float*)d_in[6];
    const float* conv1_b = (const float*)d_in[7];
    const float* convs1_w = (const float*)d_in[8];
    const float* convs1_b = (const float*)d_in[9];
    const float* conv2_w = (const float*)d_in[10];
    const float* conv2_b = (const float*)d_in[11];
    const float* convs2_w = (const float*)d_in[12];
    const float* convs2_b = (const float*)d_in[13];
    const float* lin1_w = (const float*)d_in[14];
    const float* lin1_b = (const float*)d_in[15];
    const float* lin2_w = (const float*)d_in[16];
    const float* lin2_b = (const float*)d_in[17];
    const float* lin3_w = (const float*)d_in[18];
    const float* lin3_b = (const float*)d_in[19];

    const int F1 = 128, F2 = 64;
    const int N1 = in_sizes[2];
    const int N2 = in_sizes[5];
    const int E1 = in_sizes[1] / 2;
    const int E2 = in_sizes[4] / 2;
    const int Emax = E1 > E2 ? E1 : E2;
    const int Nmax = N1 > N2 ? N1 : N2;

    char* ws = (char*)d_ws;
    size_t p = 0;
    auto alloc = [&](size_t bytes) { void* r = ws + p; p = (p + bytes + 255) & ~(size_t)255; return r; };
    float* B0     = (float*)alloc((size_t)Nmax * HD * sizeof(float));
    float* B1     = (float*)alloc((size_t)Nmax * HD * sizeof(float));
    float* dinv   = (float*)alloc((size_t)Nmax * sizeof(float));
    float* part   = (float*)alloc((size_t)PCH * NG * HD * sizeof(float));
    float* cnt    = (float*)alloc((size_t)NG * sizeof(float));
    int* deg      = (int*)alloc((size_t)Nmax * sizeof(int));
    int* off      = (int*)alloc((size_t)(Nmax + 1) * sizeof(int));
    int* cursor   = (int*)alloc((size_t)Nmax * sizeof(int));
    int* csr_src  = (int*)alloc((size_t)Emax * sizeof(int));
    float* csr_dinv = (float*)alloc((size_t)Emax * sizeof(float));
    int* bsum     = (int*)alloc(1024 * sizeof(int));
    int* bnd      = (int*)alloc((size_t)(NG + 1) * sizeof(int));

    float* out = (float*)d_out;

    run_side(x1, F1, ei1, E1, b1a, N1, conv1_w, conv1_b, convs1_w, convs1_b,
             lin1_w, lin1_b, B0, B1, dinv, part, cnt, deg, off, cursor, csr_src, csr_dinv,
             bsum, bnd, out, stream);
    run_side(x2, F2, ei2, E2, b2a, N2, conv2_w, conv2_b, convs2_w, convs2_b,
             lin2_w, lin2_b, B0, B1, dinv, part, cnt, deg, off, cursor, csr_src, csr_dinv,
             bsum, bnd, out + NG * HD, stream);

    final_kernel<<<NG, 2 * HD, 0, stream>>>(out, lin3_w, lin3_b, out);
}

// Round 3
// 710.833 us; speedup vs baseline: 2.7274x; 1.0847x over previous
//
#include <hip/hip_runtime.h>
#include <math.h>

#define HD 128   // hidden dim
#define NG 256   // num graphs
#define NC 10    // classes
#define PCH 8    // pool chunks per graph
#define NXCD 8   // XCDs on MI355X
#define CHK 16   // floats per feature chunk (64 B): per-XCD working set = N*64B = 3.2 MB < 4 MB L2

// Chunked activation layout: zc[((size_t)c * N + n) * CHK + w], c = feature chunk (= XCD), w = 0..15.

// ---------------- CSR build ----------------

__global__ void hist_kernel(const int* __restrict__ dst, int E, int* __restrict__ deg) {
    int e = blockIdx.x * blockDim.x + threadIdx.x;
    if (e < E) atomicAdd(&deg[dst[e]], 1);
}

__global__ void block_sum(const int* __restrict__ deg, int N, int* __restrict__ bsum) {
    __shared__ int sh[256];
    int i = blockIdx.x * 256 + threadIdx.x;
    sh[threadIdx.x] = (i < N) ? deg[i] : 0;
    __syncthreads();
    for (int s = 128; s > 0; s >>= 1) {
        if (threadIdx.x < s) sh[threadIdx.x] += sh[threadIdx.x + s];
        __syncthreads();
    }
    if (threadIdx.x == 0) bsum[blockIdx.x] = sh[0];
}

// parallel exclusive scan of block sums (nb <= 256)
__global__ void scan_bsum(int* __restrict__ bsum, int nb) {
    __shared__ int sh[256];
    int t = threadIdx.x;
    int v = (t < nb) ? bsum[t] : 0;
    sh[t] = v;
    __syncthreads();
    for (int s = 1; s < 256; s <<= 1) {
        int tv = 0;
        if (t >= s) tv = sh[t - s];
        __syncthreads();
        sh[t] += tv;
        __syncthreads();
    }
    if (t < nb) bsum[t] = sh[t] - v;   // exclusive
}

__global__ void scan_write(const int* __restrict__ deg, const int* __restrict__ bsum,
                           int N, int E, int* __restrict__ off, int* __restrict__ cursor,
                           float* __restrict__ dinv) {
    __shared__ int sh[256];
    int i = blockIdx.x * 256 + threadIdx.x;
    int v = (i < N) ? deg[i] : 0;
    sh[threadIdx.x] = v;
    __syncthreads();
    for (int s = 1; s < 256; s <<= 1) {
        int t = 0;
        if (threadIdx.x >= s) t = sh[threadIdx.x - s];
        __syncthreads();
        if (threadIdx.x >= s) sh[threadIdx.x] += t;
        __syncthreads();
    }
    if (i < N) {
        int excl = sh[threadIdx.x] - v + bsum[blockIdx.x];
        off[i] = excl;
        cursor[i] = excl;
        dinv[i] = rsqrtf((float)v + 1.0f);
        if (i == N - 1) off[N] = E;
    }
}

__global__ void fill_csr(const int* __restrict__ src, const int* __restrict__ dst, int E,
                         int* __restrict__ cursor, int* __restrict__ csr_src) {
    int e = blockIdx.x * blockDim.x + threadIdx.x;
    if (e < E) {
        int pos = atomicAdd(&cursor[dst[e]], 1);
        csr_src[pos] = src[e];
    }
}

// batch is sorted: graph g spans rows [lb(g), lb(g+1)). One block of NG threads.
__global__ void bounds_kernel(const int* __restrict__ batch, int N,
                              int* __restrict__ bnd, float* __restrict__ cnt) {
    int g = threadIdx.x;   // 0..NG-1
    int lo = 0, hi = N;
    while (lo < hi) { int mid = (lo + hi) >> 1; if (batch[mid] < g) lo = mid + 1; else hi = mid; }
    bnd[g] = lo;
    if (g == 0) bnd[NG] = N;
    int lo2 = lo, hi2 = N, v = g + 1;
    while (lo2 < hi2) { int mid = (lo2 + hi2) >> 1; if (batch[mid] < v) lo2 = mid + 1; else hi2 = mid; }
    cnt[g] = (float)(lo2 - lo);
}

// ---------------- conv ----------------

// LDS-tiled fp32 GEMM: z = dinv * (x @ W), written in CHUNKED layout.
// INC: input x is in chunked layout (true for layers >= 1), else row-major [N][F].
#define BM 64
#define BK 32

template <bool INC>
__global__ __launch_bounds__(256) void matmul_tiled(const float* __restrict__ x,
                                                    const float* __restrict__ W,
                                                    const float* __restrict__ dinv,
                                                    float* __restrict__ outc, int N, int F) {
    __shared__ float xl[BM][BK + 4];
    __shared__ float wl[BK][HD];
    const int tid = threadIdx.x;
    const int n0 = blockIdx.x * BM;
    const int r4 = (tid >> 4) << 2;
    const int c8 = (tid & 15) << 3;

    float acc[4][8];
#pragma unroll
    for (int i = 0; i < 4; ++i)
#pragma unroll
        for (int j = 0; j < 8; ++j) acc[i][j] = 0.f;

    for (int k0 = 0; k0 < F; k0 += BK) {
#pragma unroll
        for (int p = 0; p < 2; ++p) {
            int idx = p * 256 + tid;
            int row = idx >> 3;
            int f4 = (idx & 7) << 2;
            int n = n0 + row;
            float4 v = make_float4(0.f, 0.f, 0.f, 0.f);
            if (n < N) {
                if (INC) {
                    int kf = k0 + f4;
                    v = *(const float4*)(x + ((size_t)(kf >> 4) * N + n) * CHK + (kf & (CHK - 1)));
                } else {
                    v = *(const float4*)(x + (size_t)n * F + k0 + f4);
                }
            }
            *(float4*)&xl[row][f4] = v;
        }
#pragma unroll
        for (int p = 0; p < 4; ++p) {
            int idx = p * 256 + tid;
            int kk = idx >> 5;
            int j4 = (idx & 31) << 2;
            *(float4*)&wl[kk][j4] = *(const float4*)(W + (size_t)(k0 + kk) * HD + j4);
        }
        __syncthreads();

#pragma unroll 8
        for (int kk = 0; kk < BK; ++kk) {
            float av[4];
            av[0] = xl[r4 + 0][kk];
            av[1] = xl[r4 + 1][kk];
            av[2] = xl[r4 + 2][kk];
            av[3] = xl[r4 + 3][kk];
            float4 w0 = *(const float4*)&wl[kk][c8];
            float4 w1 = *(const float4*)&wl[kk][c8 + 4];
            float wv[8] = {w0.x, w0.y, w0.z, w0.w, w1.x, w1.y, w1.z, w1.w};
#pragma unroll
            for (int i = 0; i < 4; ++i)
#pragma unroll
                for (int j = 0; j < 8; ++j)
                    acc[i][j] += av[i] * wv[j];
        }
        __syncthreads();
    }

    // epilogue: scale by dinv[n], store chunked (c8 is 8-aligned -> both float4s in one chunk)
#pragma unroll
    for (int i = 0; i < 4; ++i) {
        int n = n0 + r4 + i;
        if (n < N) {
            float dn = dinv[n];
            float4 o0 = make_float4(acc[i][0] * dn, acc[i][1] * dn, acc[i][2] * dn, acc[i][3] * dn);
            float4 o1 = make_float4(acc[i][4] * dn, acc[i][5] * dn, acc[i][6] * dn, acc[i][7] * dn);
            float* a = outc + ((size_t)(c8 >> 4) * N + n) * CHK + (c8 & (CHK - 1));
            *(float4*)a = o0;
            *(float4*)(a + 4) = o1;
        }
    }
}

// Chunk-resident gather: block (c, nr) aggregates chunk c (16 floats) for nodes nr*64..+63.
// blockIdx.x = c = XCD id (round-robin dispatch) -> per-XCD L2 working set 3.2 MB, L2-hit bound.
// out[n] = (sum_src z[src] + z[n]) * dinv[n] + b, relu; z = dinv*(xW) precomputed by matmul.
__global__ __launch_bounds__(256) void gather_chunked(const int* __restrict__ off,
                                                      const int* __restrict__ csr_src,
                                                      const float* __restrict__ dinv,
                                                      const float* __restrict__ zc,
                                                      const float* __restrict__ b,
                                                      float* __restrict__ outc, int N) {
    int c = blockIdx.x;                               // feature chunk = XCD
    int n = blockIdx.y * 64 + (threadIdx.x >> 2);     // 4 lanes per node
    if (n >= N) return;
    int l4 = (threadIdx.x & 3) << 2;                  // float4 slot within chunk
    const float* base = zc + (size_t)c * N * CHK + l4;
    float dn = dinv[n];
    int e0 = off[n], e1 = off[n + 1];
    float ax0 = 0.f, ay0 = 0.f, az0 = 0.f, aw0 = 0.f;
    float ax1 = 0.f, ay1 = 0.f, az1 = 0.f, aw1 = 0.f;
    float ax2 = 0.f, ay2 = 0.f, az2 = 0.f, aw2 = 0.f;
    float ax3 = 0.f, ay3 = 0.f, az3 = 0.f, aw3 = 0.f;
    int e = e0;
    for (; e + 4 <= e1; e += 4) {
        int s0 = csr_src[e + 0];
        int s1 = csr_src[e + 1];
        int s2 = csr_src[e + 2];
        int s3 = csr_src[e + 3];
        const float4 v0 = *(const float4*)(base + (size_t)s0 * CHK);
        const float4 v1 = *(const float4*)(base + (size_t)s1 * CHK);
        const float4 v2 = *(const float4*)(base + (size_t)s2 * CHK);
        const float4 v3 = *(const float4*)(base + (size_t)s3 * CHK);
        ax0 += v0.x; ay0 += v0.y; az0 += v0.z; aw0 += v0.w;
        ax1 += v1.x; ay1 += v1.y; az1 += v1.z; aw1 += v1.w;
        ax2 += v2.x; ay2 += v2.y; az2 += v2.z; aw2 += v2.w;
        ax3 += v3.x; ay3 += v3.y; az3 += v3.z; aw3 += v3.w;
    }
    for (; e < e1; ++e) {
        int s = csr_src[e];
        const float4 v = *(const float4*)(base + (size_t)s * CHK);
        ax0 += v.x; ay0 += v.y; az0 += v.z; aw0 += v.w;
    }
    float ax = (ax0 + ax1) + (ax2 + ax3);
    float ay = (ay0 + ay1) + (ay2 + ay3);
    float az = (az0 + az1) + (az2 + az3);
    float aw = (aw0 + aw1) + (aw2 + aw3);
    const float4 zs = *(const float4*)(base + (size_t)n * CHK);
    const float4 bb = *(const float4*)(b + c * CHK + l4);
    float4 o;
    o.x = (ax + zs.x) * dn + bb.x;
    o.y = (ay + zs.y) * dn + bb.y;
    o.z = (az + zs.z) * dn + bb.z;
    o.w = (aw + zs.w) * dn + bb.w;
    o.x = o.x > 0.f ? o.x : 0.f;
    o.y = o.y > 0.f ? o.y : 0.f;
    o.z = o.z > 0.f ? o.z : 0.f;
    o.w = o.w > 0.f ? o.w : 0.f;
    *(float4*)(outc + ((size_t)c * N + n) * CHK + l4) = o;
}

// ---------------- pooling + head ----------------

// per-graph chunked pool over CHUNKED h: block (g, cch) sums rows [bnd[g]+cch :: PCH : bnd[g+1]).
__global__ void pool_kernel(const float* __restrict__ h, const int* __restrict__ bnd,
                            float* __restrict__ part, int N) {
    int g = blockIdx.x;
    int cch = blockIdx.y;
    int j = threadIdx.x;   // HD threads; feature j lives at chunk j>>4, word j&15
    size_t fo = ((size_t)(j >> 4) * N) * CHK + (j & (CHK - 1));
    int s = bnd[g], e = bnd[g + 1];
    float acc = 0.f;
    for (int n = s + cch; n < e; n += PCH) acc += h[fo + (size_t)n * CHK];
    part[((size_t)cch * NG + g) * HD + j] = acc;
}

__global__ void lin_kernel(const float* __restrict__ part, const float* __restrict__ cnt,
                           const float* __restrict__ W, const float* __restrict__ b,
                           float* __restrict__ out) {
    __shared__ float row[HD];
    int g = blockIdx.x, j = threadIdx.x;
    float s0 = 0.f;
#pragma unroll
    for (int c = 0; c < PCH; ++c) s0 += part[((size_t)c * NG + g) * HD + j];
    float c = cnt[g];
    c = c > 1.f ? c : 1.f;
    row[j] = s0 / c;
    __syncthreads();
    float s = b[j];
#pragma unroll 8
    for (int k = 0; k < HD; ++k) s += row[k] * W[k * HD + j];
    out[g * HD + j] = s > 0.f ? s : 0.f;
}

__global__ void final_kernel(const float* __restrict__ outg,
                             const float* __restrict__ W3, const float* __restrict__ b3,
                             float* __restrict__ out) {
    __shared__ float c[2 * HD];
    __shared__ float logit[NC];
    __shared__ float lse;
    int g = blockIdx.x, t = threadIdx.x;   // 256 threads
    c[t] = (t < HD) ? outg[g * HD + t] : outg[NG * HD + g * HD + (t - HD)];
    __syncthreads();
    if (t < NC) {
        float s = b3[t];
#pragma unroll 8
        for (int k = 0; k < 2 * HD; ++k) s += c[k] * W3[k * NC + t];
        logit[t] = s;
    }
    __syncthreads();
    if (t == 0) {
        float m = logit[0];
        for (int i = 1; i < NC; ++i) m = fmaxf(m, logit[i]);
        float s = 0.f;
        for (int i = 0; i < NC; ++i) s += expf(logit[i] - m);
        lse = m + logf(s);
    }
    __syncthreads();
    if (t < NC) out[2 * NG * HD + g * NC + t] = logit[t] - lse;
}

// ---------------- host side ----------------

static void run_side(const float* x, int F, const int* ei, int E, const int* batch, int N,
                     const float* w1, const float* b1,
                     const float* ws_w, const float* ws_b,
                     const float* lin_w, const float* lin_b,
                     float* B0, float* B1, float* dinv, float* part, float* cnt,
                     int* deg, int* off, int* cursor, int* csr_src,
                     int* bsum, int* bnd,
                     float* out_sec, hipStream_t stream) {
    const int* src = ei;
    const int* dst = ei + E;
    const int nb = (N + 255) / 256;

    // CSR build (once per side, reused for 3 layers)
    hipMemsetAsync(deg, 0, (size_t)N * sizeof(int), stream);
    hist_kernel<<<(E + 255) / 256, 256, 0, stream>>>(dst, E, deg);
    block_sum<<<nb, 256, 0, stream>>>(deg, N, bsum);
    scan_bsum<<<1, 256, 0, stream>>>(bsum, nb);
    scan_write<<<nb, 256, 0, stream>>>(deg, bsum, N, E, off, cursor, dinv);
    fill_csr<<<(E + 255) / 256, 256, 0, stream>>>(src, dst, E, cursor, csr_src);
    bounds_kernel<<<1, NG, 0, stream>>>(batch, N, bnd, cnt);

    const int mm_blocks = (N + BM - 1) / BM;
    const dim3 ga_grid(NXCD, (N + 63) / 64);

    const float* hin = x;
    int Fin = F;
    for (int l = 0; l < 3; ++l) {
        const float* W = (l == 0) ? w1 : ws_w + (size_t)(l - 1) * HD * HD;
        const float* b = (l == 0) ? b1 : ws_b + (size_t)(l - 1) * HD;
        if (l == 0)
            matmul_tiled<false><<<mm_blocks, 256, 0, stream>>>(hin, W, dinv, B0, N, Fin);
        else
            matmul_tiled<true><<<mm_blocks, 256, 0, stream>>>(hin, W, dinv, B0, N, Fin);
        gather_chunked<<<ga_grid, 256, 0, stream>>>(off, csr_src, dinv, B0, b, B1, N);
        hin = B1;
        Fin = HD;
    }

    pool_kernel<<<dim3(NG, PCH), HD, 0, stream>>>(B1, bnd, part, N);
    lin_kernel<<<NG, HD, 0, stream>>>(part, cnt, lin_w, lin_b, out_sec);
}

extern "C" void kernel_launch(void* const* d_in, const int* in_sizes, int n_in,
                              void* d_out, int out_size, void* d_ws, size_t ws_size,
                              hipStream_t stream) {
    const float* x1  = (const float*)d_in[0];
    const int*   ei1 = (const int*)d_in[1];
    const int*   b1a = (const int*)d_in[2];
    const float* x2  = (const float*)d_in[3];
    const int*   ei2 = (const int*)d_in[4];
    const int*   b2a = (const int*)d_in[5];
    const float* conv1_w = (const float*)d_in[6];
    const float* conv1_b = (const float*)d_in[7];
    const float* convs1_w = (const float*)d_in[8];
    const float* convs1_b = (const float*)d_in[9];
    const float* conv2_w = (const float*)d_in[10];
    const float* conv2_b = (const float*)d_in[11];
    const float* convs2_w = (const float*)d_in[12];
    const float* convs2_b = (const float*)d_in[13];
    const float* lin1_w = (const float*)d_in[14];
    const float* lin1_b = (const float*)d_in[15];
    const float* lin2_w = (const float*)d_in[16];
    const float* lin2_b = (const float*)d_in[17];
    const float* lin3_w = (const float*)d_in[18];
    const float* lin3_b = (const float*)d_in[19];

    const int F1 = 128, F2 = 64;
    const int N1 = in_sizes[2];
    const int N2 = in_sizes[5];
    const int E1 = in_sizes[1] / 2;
    const int E2 = in_sizes[4] / 2;
    const int Emax = E1 > E2 ? E1 : E2;
    const int Nmax = N1 > N2 ? N1 : N2;

    char* ws = (char*)d_ws;
    size_t p = 0;
    auto alloc = [&](size_t bytes) { void* r = ws + p; p = (p + bytes + 255) & ~(size_t)255; return r; };
    float* B0     = (float*)alloc((size_t)Nmax * HD * sizeof(float));
    float* B1     = (float*)alloc((size_t)Nmax * HD * sizeof(float));
    float* dinv   = (float*)alloc((size_t)Nmax * sizeof(float));
    float* part   = (float*)alloc((size_t)PCH * NG * HD * sizeof(float));
    float* cnt    = (float*)alloc((size_t)NG * sizeof(float));
    int* deg      = (int*)alloc((size_t)Nmax * sizeof(int));
    int* off      = (int*)alloc((size_t)(Nmax + 1) * sizeof(int));
    int* cursor   = (int*)alloc((size_t)Nmax * sizeof(int));
    int* csr_src  = (int*)alloc((size_t)Emax * sizeof(int));
    int* bsum     = (int*)alloc(1024 * sizeof(int));
    int* bnd      = (int*)alloc((size_t)(NG + 1) * sizeof(int));

    float* out = (float*)d_out;

    run_side(x1, F1, ei1, E1, b1a, N1, conv1_w, conv1_b, convs1_w, convs1_b,
             lin1_w, lin1_b, B0, B1, dinv, part, cnt, deg, off, cursor, csr_src,
             bsum, bnd, out, stream);
    run_side(x2, F2, ei2, E2, b2a, N2, conv2_w, conv2_b, convs2_w, convs2_b,
             lin2_w, lin2_b, B0, B1, dinv, part, cnt, deg, off, cursor, csr_src,
             bsum, bnd, out + NG * HD, stream);

    final_kernel<<<NG, 2 * HD, 0, stream>>>(out, lin3_w, lin3_b, out);
}

// Round 4
// 682.798 us; speedup vs baseline: 2.8394x; 1.0411x over previous
//
#include <hip/hip_runtime.h>
#include <math.h>

#define HD 128   // hidden dim
#define NG 256   // num graphs
#define NC 10    // classes
#define PCH 8    // pool chunks per graph
#define NXCD 8   // XCDs on MI355X
#define CHK 16   // floats per feature chunk (64 B): per-XCD working set = N*64B = 3.2 MB < 4 MB L2

// Chunked activation layout: zc[((size_t)c * N + n) * CHK + w], c = feature chunk (= XCD), w = 0..15.

// ---------------- CSR build ----------------

// XCD-range-filtered histogram: block b owns node range (b&7) (= its XCD under round-robin
// dispatch). Each edge is READ by all 8 ranges but COUNTED by exactly one -> deg/cursor lines
// are single-XCD-owned, no cross-XCD line bouncing. Correct under any block->XCD mapping.
__global__ __launch_bounds__(256) void hist_x(const int* __restrict__ dst, int E, int N,
                                              int* __restrict__ deg) {
    int r = blockIdx.x & (NXCD - 1);
    int lo = (int)(((long long)N * r) >> 3);
    int hi = (int)(((long long)N * (r + 1)) >> 3);
    int nb = gridDim.x >> 3;
    int cb = blockIdx.x >> 3;
    int stride = nb * 256;
    for (int e = cb * 256 + threadIdx.x; e < E; e += stride) {
        int d = dst[e];
        if (d >= lo && d < hi) atomicAdd(&deg[d], 1);
    }
}

// XCD-range-filtered CSR fill: csr_src segment for a node is written only by its owning XCD
// -> full 64B lines accumulate in local L2, writeback once (kills the 16x write amplification).
__global__ __launch_bounds__(256) void fill_x(const int* __restrict__ src,
                                              const int* __restrict__ dst, int E, int N,
                                              int* __restrict__ cursor, int* __restrict__ csr_src) {
    int r = blockIdx.x & (NXCD - 1);
    int lo = (int)(((long long)N * r) >> 3);
    int hi = (int)(((long long)N * (r + 1)) >> 3);
    int nb = gridDim.x >> 3;
    int cb = blockIdx.x >> 3;
    int stride = nb * 256;
    for (int e = cb * 256 + threadIdx.x; e < E; e += stride) {
        int d = dst[e];
        if (d >= lo && d < hi) {
            int pos = atomicAdd(&cursor[d], 1);
            csr_src[pos] = src[e];
        }
    }
}

__global__ void block_sum(const int* __restrict__ deg, int N, int* __restrict__ bsum) {
    __shared__ int sh[256];
    int i = blockIdx.x * 256 + threadIdx.x;
    sh[threadIdx.x] = (i < N) ? deg[i] : 0;
    __syncthreads();
    for (int s = 128; s > 0; s >>= 1) {
        if (threadIdx.x < s) sh[threadIdx.x] += sh[threadIdx.x + s];
        __syncthreads();
    }
    if (threadIdx.x == 0) bsum[blockIdx.x] = sh[0];
}

// parallel exclusive scan of block sums (nb <= 256)
__global__ void scan_bsum(int* __restrict__ bsum, int nb) {
    __shared__ int sh[256];
    int t = threadIdx.x;
    int v = (t < nb) ? bsum[t] : 0;
    sh[t] = v;
    __syncthreads();
    for (int s = 1; s < 256; s <<= 1) {
        int tv = 0;
        if (t >= s) tv = sh[t - s];
        __syncthreads();
        sh[t] += tv;
        __syncthreads();
    }
    if (t < nb) bsum[t] = sh[t] - v;   // exclusive
}

__global__ void scan_write(const int* __restrict__ deg, const int* __restrict__ bsum,
                           int N, int E, int* __restrict__ off, int* __restrict__ cursor,
                           float* __restrict__ dinv) {
    __shared__ int sh[256];
    int i = blockIdx.x * 256 + threadIdx.x;
    int v = (i < N) ? deg[i] : 0;
    sh[threadIdx.x] = v;
    __syncthreads();
    for (int s = 1; s < 256; s <<= 1) {
        int t = 0;
        if (threadIdx.x >= s) t = sh[threadIdx.x - s];
        __syncthreads();
        if (threadIdx.x >= s) sh[threadIdx.x] += t;
        __syncthreads();
    }
    if (i < N) {
        int excl = sh[threadIdx.x] - v + bsum[blockIdx.x];
        off[i] = excl;
        cursor[i] = excl;
        dinv[i] = rsqrtf((float)v + 1.0f);
        if (i == N - 1) off[N] = E;
    }
}

// batch is sorted: graph g spans rows [lb(g), lb(g+1)). One block of NG threads.
__global__ void bounds_kernel(const int* __restrict__ batch, int N,
                              int* __restrict__ bnd, float* __restrict__ cnt) {
    int g = threadIdx.x;   // 0..NG-1
    int lo = 0, hi = N;
    while (lo < hi) { int mid = (lo + hi) >> 1; if (batch[mid] < g) lo = mid + 1; else hi = mid; }
    bnd[g] = lo;
    if (g == 0) bnd[NG] = N;
    int lo2 = lo, hi2 = N, v = g + 1;
    while (lo2 < hi2) { int mid = (lo2 + hi2) >> 1; if (batch[mid] < v) lo2 = mid + 1; else hi2 = mid; }
    cnt[g] = (float)(lo2 - lo);
}

// ---------------- conv ----------------

// LDS-tiled fp32 GEMM: z = dinv * (x @ W), written in CHUNKED layout.
// INC: input x is in chunked layout (true for layers >= 1), else row-major [N][F].
#define BM 64
#define BK 32

template <bool INC>
__global__ __launch_bounds__(256) void matmul_tiled(const float* __restrict__ x,
                                                    const float* __restrict__ W,
                                                    const float* __restrict__ dinv,
                                                    float* __restrict__ outc, int N, int F) {
    __shared__ float xl[BM][BK + 4];
    __shared__ float wl[BK][HD];
    const int tid = threadIdx.x;
    const int n0 = blockIdx.x * BM;
    const int r4 = (tid >> 4) << 2;
    const int c8 = (tid & 15) << 3;

    float acc[4][8];
#pragma unroll
    for (int i = 0; i < 4; ++i)
#pragma unroll
        for (int j = 0; j < 8; ++j) acc[i][j] = 0.f;

    for (int k0 = 0; k0 < F; k0 += BK) {
#pragma unroll
        for (int p = 0; p < 2; ++p) {
            int idx = p * 256 + tid;
            int row = idx >> 3;
            int f4 = (idx & 7) << 2;
            int n = n0 + row;
            float4 v = make_float4(0.f, 0.f, 0.f, 0.f);
            if (n < N) {
                if (INC) {
                    int kf = k0 + f4;
                    v = *(const float4*)(x + ((size_t)(kf >> 4) * N + n) * CHK + (kf & (CHK - 1)));
                } else {
                    v = *(const float4*)(x + (size_t)n * F + k0 + f4);
                }
            }
            *(float4*)&xl[row][f4] = v;
        }
#pragma unroll
        for (int p = 0; p < 4; ++p) {
            int idx = p * 256 + tid;
            int kk = idx >> 5;
            int j4 = (idx & 31) << 2;
            *(float4*)&wl[kk][j4] = *(const float4*)(W + (size_t)(k0 + kk) * HD + j4);
        }
        __syncthreads();

#pragma unroll 8
        for (int kk = 0; kk < BK; ++kk) {
            float av[4];
            av[0] = xl[r4 + 0][kk];
            av[1] = xl[r4 + 1][kk];
            av[2] = xl[r4 + 2][kk];
            av[3] = xl[r4 + 3][kk];
            float4 w0 = *(const float4*)&wl[kk][c8];
            float4 w1 = *(const float4*)&wl[kk][c8 + 4];
            float wv[8] = {w0.x, w0.y, w0.z, w0.w, w1.x, w1.y, w1.z, w1.w};
#pragma unroll
            for (int i = 0; i < 4; ++i)
#pragma unroll
                for (int j = 0; j < 8; ++j)
                    acc[i][j] += av[i] * wv[j];
        }
        __syncthreads();
    }

    // epilogue: scale by dinv[n], store chunked (c8 is 8-aligned -> both float4s in one chunk)
#pragma unroll
    for (int i = 0; i < 4; ++i) {
        int n = n0 + r4 + i;
        if (n < N) {
            float dn = dinv[n];
            float4 o0 = make_float4(acc[i][0] * dn, acc[i][1] * dn, acc[i][2] * dn, acc[i][3] * dn);
            float4 o1 = make_float4(acc[i][4] * dn, acc[i][5] * dn, acc[i][6] * dn, acc[i][7] * dn);
            float* a = outc + ((size_t)(c8 >> 4) * N + n) * CHK + (c8 & (CHK - 1));
            *(float4*)a = o0;
            *(float4*)(a + 4) = o1;
        }
    }
}

// Chunk-resident gather: block (c, nr) aggregates chunk c (16 floats) for nodes nr*64..+63.
// blockIdx.x = c = XCD id (round-robin dispatch) -> per-XCD L2 working set 3.2 MB, L2-hit bound.
// out[n] = (sum_src z[src] + z[n]) * dinv[n] + b, relu; z = dinv*(xW) precomputed by matmul.
__global__ __launch_bounds__(256) void gather_chunked(const int* __restrict__ off,
                                                      const int* __restrict__ csr_src,
                                                      const float* __restrict__ dinv,
                                                      const float* __restrict__ zc,
                                                      const float* __restrict__ b,
                                                      float* __restrict__ outc, int N) {
    int c = blockIdx.x;                               // feature chunk = XCD
    int n = blockIdx.y * 64 + (threadIdx.x >> 2);     // 4 lanes per node
    if (n >= N) return;
    int l4 = (threadIdx.x & 3) << 2;                  // float4 slot within chunk
    const float* base = zc + (size_t)c * N * CHK + l4;
    float dn = dinv[n];
    int e0 = off[n], e1 = off[n + 1];
    float ax0 = 0.f, ay0 = 0.f, az0 = 0.f, aw0 = 0.f;
    float ax1 = 0.f, ay1 = 0.f, az1 = 0.f, aw1 = 0.f;
    float ax2 = 0.f, ay2 = 0.f, az2 = 0.f, aw2 = 0.f;
    float ax3 = 0.f, ay3 = 0.f, az3 = 0.f, aw3 = 0.f;
    int e = e0;
    for (; e + 4 <= e1; e += 4) {
        int s0 = csr_src[e + 0];
        int s1 = csr_src[e + 1];
        int s2 = csr_src[e + 2];
        int s3 = csr_src[e + 3];
        const float4 v0 = *(const float4*)(base + (size_t)s0 * CHK);
        const float4 v1 = *(const float4*)(base + (size_t)s1 * CHK);
        const float4 v2 = *(const float4*)(base + (size_t)s2 * CHK);
        const float4 v3 = *(const float4*)(base + (size_t)s3 * CHK);
        ax0 += v0.x; ay0 += v0.y; az0 += v0.z; aw0 += v0.w;
        ax1 += v1.x; ay1 += v1.y; az1 += v1.z; aw1 += v1.w;
        ax2 += v2.x; ay2 += v2.y; az2 += v2.z; aw2 += v2.w;
        ax3 += v3.x; ay3 += v3.y; az3 += v3.z; aw3 += v3.w;
    }
    for (; e < e1; ++e) {
        int s = csr_src[e];
        const float4 v = *(const float4*)(base + (size_t)s * CHK);
        ax0 += v.x; ay0 += v.y; az0 += v.z; aw0 += v.w;
    }
    float ax = (ax0 + ax1) + (ax2 + ax3);
    float ay = (ay0 + ay1) + (ay2 + ay3);
    float az = (az0 + az1) + (az2 + az3);
    float aw = (aw0 + aw1) + (aw2 + aw3);
    const float4 zs = *(const float4*)(base + (size_t)n * CHK);
    const float4 bb = *(const float4*)(b + c * CHK + l4);
    float4 o;
    o.x = (ax + zs.x) * dn + bb.x;
    o.y = (ay + zs.y) * dn + bb.y;
    o.z = (az + zs.z) * dn + bb.z;
    o.w = (aw + zs.w) * dn + bb.w;
    o.x = o.x > 0.f ? o.x : 0.f;
    o.y = o.y > 0.f ? o.y : 0.f;
    o.z = o.z > 0.f ? o.z : 0.f;
    o.w = o.w > 0.f ? o.w : 0.f;
    *(float4*)(outc + ((size_t)c * N + n) * CHK + l4) = o;
}

// ---------------- pooling + head ----------------

// per-graph chunked pool over CHUNKED h: block (g, cch) sums rows [bnd[g]+cch :: PCH : bnd[g+1]).
__global__ void pool_kernel(const float* __restrict__ h, const int* __restrict__ bnd,
                            float* __restrict__ part, int N) {
    int g = blockIdx.x;
    int cch = blockIdx.y;
    int j = threadIdx.x;   // HD threads; feature j lives at chunk j>>4, word j&15
    size_t fo = ((size_t)(j >> 4) * N) * CHK + (j & (CHK - 1));
    int s = bnd[g], e = bnd[g + 1];
    float acc = 0.f;
    for (int n = s + cch; n < e; n += PCH) acc += h[fo + (size_t)n * CHK];
    part[((size_t)cch * NG + g) * HD + j] = acc;
}

__global__ void lin_kernel(const float* __restrict__ part, const float* __restrict__ cnt,
                           const float* __restrict__ W, const float* __restrict__ b,
                           float* __restrict__ out) {
    __shared__ float row[HD];
    int g = blockIdx.x, j = threadIdx.x;
    float s0 = 0.f;
#pragma unroll
    for (int c = 0; c < PCH; ++c) s0 += part[((size_t)c * NG + g) * HD + j];
    float c = cnt[g];
    c = c > 1.f ? c : 1.f;
    row[j] = s0 / c;
    __syncthreads();
    float s = b[j];
#pragma unroll 8
    for (int k = 0; k < HD; ++k) s += row[k] * W[k * HD + j];
    out[g * HD + j] = s > 0.f ? s : 0.f;
}

__global__ void final_kernel(const float* __restrict__ outg,
                             const float* __restrict__ W3, const float* __restrict__ b3,
                             float* __restrict__ out) {
    __shared__ float c[2 * HD];
    __shared__ float logit[NC];
    __shared__ float lse;
    int g = blockIdx.x, t = threadIdx.x;   // 256 threads
    c[t] = (t < HD) ? outg[g * HD + t] : outg[NG * HD + g * HD + (t - HD)];
    __syncthreads();
    if (t < NC) {
        float s = b3[t];
#pragma unroll 8
        for (int k = 0; k < 2 * HD; ++k) s += c[k] * W3[k * NC + t];
        logit[t] = s;
    }
    __syncthreads();
    if (t == 0) {
        float m = logit[0];
        for (int i = 1; i < NC; ++i) m = fmaxf(m, logit[i]);
        float s = 0.f;
        for (int i = 0; i < NC; ++i) s += expf(logit[i] - m);
        lse = m + logf(s);
    }
    __syncthreads();
    if (t < NC) out[2 * NG * HD + g * NC + t] = logit[t] - lse;
}

// ---------------- host side ----------------

static void run_side(const float* x, int F, const int* ei, int E, const int* batch, int N,
                     const float* w1, const float* b1,
                     const float* ws_w, const float* ws_b,
                     const float* lin_w, const float* lin_b,
                     float* B0, float* B1, float* dinv, float* part, float* cnt,
                     int* deg, int* off, int* cursor, int* csr_src,
                     int* bsum, int* bnd,
                     float* out_sec, hipStream_t stream) {
    const int* src = ei;
    const int* dst = ei + E;
    const int nb = (N + 255) / 256;

    // CSR build (once per side, reused for 3 layers)
    hipMemsetAsync(deg, 0, (size_t)N * sizeof(int), stream);
    hist_x<<<2048, 256, 0, stream>>>(dst, E, N, deg);
    block_sum<<<nb, 256, 0, stream>>>(deg, N, bsum);
    scan_bsum<<<1, 256, 0, stream>>>(bsum, nb);
    scan_write<<<nb, 256, 0, stream>>>(deg, bsum, N, E, off, cursor, dinv);
    fill_x<<<2048, 256, 0, stream>>>(src, dst, E, N, cursor, csr_src);
    bounds_kernel<<<1, NG, 0, stream>>>(batch, N, bnd, cnt);

    const int mm_blocks = (N + BM - 1) / BM;
    const dim3 ga_grid(NXCD, (N + 63) / 64);

    const float* hin = x;
    int Fin = F;
    for (int l = 0; l < 3; ++l) {
        const float* W = (l == 0) ? w1 : ws_w + (size_t)(l - 1) * HD * HD;
        const float* b = (l == 0) ? b1 : ws_b + (size_t)(l - 1) * HD;
        if (l == 0)
            matmul_tiled<false><<<mm_blocks, 256, 0, stream>>>(hin, W, dinv, B0, N, Fin);
        else
            matmul_tiled<true><<<mm_blocks, 256, 0, stream>>>(hin, W, dinv, B0, N, Fin);
        gather_chunked<<<ga_grid, 256, 0, stream>>>(off, csr_src, dinv, B0, b, B1, N);
        hin = B1;
        Fin = HD;
    }

    pool_kernel<<<dim3(NG, PCH), HD, 0, stream>>>(B1, bnd, part, N);
    lin_kernel<<<NG, HD, 0, stream>>>(part, cnt, lin_w, lin_b, out_sec);
}

extern "C" void kernel_launch(void* const* d_in, const int* in_sizes, int n_in,
                              void* d_out, int out_size, void* d_ws, size_t ws_size,
                              hipStream_t stream) {
    const float* x1  = (const float*)d_in[0];
    const int*   ei1 = (const int*)d_in[1];
    const int*   b1a = (const int*)d_in[2];
    const float* x2  = (const float*)d_in[3];
    const int*   ei2 = (const int*)d_in[4];
    const int*   b2a = (const int*)d_in[5];
    const float* conv1_w = (const float*)d_in[6];
    const float* conv1_b = (const float*)d_in[7];
    const float* convs1_w = (const float*)d_in[8];
    const float* convs1_b = (const float*)d_in[9];
    const float* conv2_w = (const float*)d_in[10];
    const float* conv2_b = (const float*)d_in[11];
    const float* convs2_w = (const float*)d_in[12];
    const float* convs2_b = (const float*)d_in[13];
    const float* lin1_w = (const float*)d_in[14];
    const float* lin1_b = (const float*)d_in[15];
    const float* lin2_w = (const float*)d_in[16];
    const float* lin2_b = (const float*)d_in[17];
    const float* lin3_w = (const float*)d_in[18];
    const float* lin3_b = (const float*)d_in[19];

    const int F1 = 128, F2 = 64;
    const int N1 = in_sizes[2];
    const int N2 = in_sizes[5];
    const int E1 = in_sizes[1] / 2;
    const int E2 = in_sizes[4] / 2;
    const int Emax = E1 > E2 ? E1 : E2;
    const int Nmax = N1 > N2 ? N1 : N2;

    char* ws = (char*)d_ws;
    size_t p = 0;
    auto alloc = [&](size_t bytes) { void* r = ws + p; p = (p + bytes + 255) & ~(size_t)255; return r; };
    float* B0     = (float*)alloc((size_t)Nmax * HD * sizeof(float));
    float* B1     = (float*)alloc((size_t)Nmax * HD * sizeof(float));
    float* dinv   = (float*)alloc((size_t)Nmax * sizeof(float));
    float* part   = (float*)alloc((size_t)PCH * NG * HD * sizeof(float));
    float* cnt    = (float*)alloc((size_t)NG * sizeof(float));
    int* deg      = (int*)alloc((size_t)Nmax * sizeof(int));
    int* off      = (int*)alloc((size_t)(Nmax + 1) * sizeof(int));
    int* cursor   = (int*)alloc((size_t)Nmax * sizeof(int));
    int* csr_src  = (int*)alloc((size_t)Emax * sizeof(int));
    int* bsum     = (int*)alloc(1024 * sizeof(int));
    int* bnd      = (int*)alloc((size_t)(NG + 1) * sizeof(int));

    float* out = (float*)d_out;

    run_side(x1, F1, ei1, E1, b1a, N1, conv1_w, conv1_b, convs1_w, convs1_b,
             lin1_w, lin1_b, B0, B1, dinv, part, cnt, deg, off, cursor, csr_src,
             bsum, bnd, out, stream);
    run_side(x2, F2, ei2, E2, b2a, N2, conv2_w, conv2_b, convs2_w, convs2_b,
             lin2_w, lin2_b, B0, B1, dinv, part, cnt, deg, off, cursor, csr_src,
             bsum, bnd, out + NG * HD, stream);

    final_kernel<<<NG, 2 * HD, 0, stream>>>(out, lin3_w, lin3_b, out);
}